// Round 10
// baseline (1011.531 us; speedup 1.0000x reference)
//
#include <hip/hip_runtime.h>
#include <hip/hip_fp16.h>
#include <stdint.h>
#include <math.h>

#define HWS 16384
#define NPIX (16 * HWS)
#define T 256

// Folded parameter table in d_ws (offsets in 4-byte slots).
// "H_" tables hold packed half2 pairs (two fp16 weights per slot);
// all others are fp32.
enum {
  OFF_W1T  = 0,      // H [48c][12 o-pairs] rb conv1
  OFF_B1   = 576,    // 24 f32
  OFF_W2R  = 600,    // H [48o][12 c-pairs] rb conv2
  OFF_B2   = 1176,   // 48
  OFF_XS   = 1224,   // 48
  OFF_M1A  = 1272,   // H [48c][12 j-pairs] score folds
  OFF_M1B  = 1848,
  OFF_M2A  = 2424,
  OFF_M2B  = 3000,
  OFF_C1A  = 3576,   // 48 f32 each
  OFF_C1B  = 3624,
  OFF_C2A  = 3672,
  OFF_C2B  = 3720,
  OFF_D1A  = 3768,   // 24 f32 each
  OFF_D1B  = 3792,
  OFF_D2A  = 3816,
  OFF_D2B  = 3840,
  OFF_E4   = 3864,   // 4 f32
  OFF_P1L  = 3868,   // H [48c][12 o-pairs] value->emb1 folds
  OFF_P1H  = 4444,
  OFF_P2L  = 5020,
  OFF_P2H  = 5596,
  OFF_Q1L  = 6172,   // 24 f32 each
  OFF_Q1H  = 6196,
  OFF_Q2L  = 6220,
  OFF_Q2H  = 6244,
  OFF_BE1  = 6268,   // 24
  OFF_CFT  = 6292,   // f32 [96][48] cin-major (k0 only)
  OFF_BCF  = 10900,  // 48
  OFF_WE1  = 10948,  // f32 [24][48] o-major (k0 only)
  OFF_BE2  = 12100,  // 48
  OFF_WE2R = 12148,  // f32 [48][24] o-major (final only)
  WS_TOTAL = 13300
};

struct PtrPack { const float* p[48]; };

__device__ __forceinline__ void bnst(const PtrPack& P, int bnb, int o, float& s, float& t) {
  float g = P.p[bnb][o], be = P.p[bnb + 1][o], m = P.p[bnb + 2][o], v = P.p[bnb + 3][o];
  s = g / sqrtf(v + 1e-5f);
  t = be - m * s;
}
__device__ __forceinline__ float KFv(const PtrPack& P, const float* kw, int bnb, int ok, int j) {
  float s, t; bnst(P, bnb, ok, s, t);
  float a = 0.f;
  for (int cc = 0; cc < 48; cc++) a += kw[ok * 48 + cc] * P.p[46][cc * 24 + j];
  return s * a;
}
__device__ __forceinline__ float BFv(const PtrPack& P, const float* kw, const float* kb, int bnb, int ok) {
  float s, t; bnst(P, bnb, ok, s, t);
  float a = kb[ok];
  for (int cc = 0; cc < 48; cc++) a += kw[ok * 48 + cc] * P.p[47][cc];
  return s * a + t;
}
__device__ __forceinline__ float WQf(const PtrPack& P, int o, int c) { float s, t; bnst(P, 16, o, s, t); return s * P.p[14][o * 48 + c]; }
__device__ __forceinline__ float BQf(const PtrPack& P, int o) { float s, t; bnst(P, 16, o, s, t); return s * P.p[15][o] + t; }
__device__ __forceinline__ float WVf(const PtrPack& P, int o, int c) { float s, t; bnst(P, 22, o, s, t); return s * P.p[20][o * 48 + c]; }
__device__ __forceinline__ float BVf(const PtrPack& P, int o) { float s, t; bnst(P, 22, o, s, t); return s * P.p[21][o] + t; }

// per-element generators for the pair tables
__device__ float w1t_v(const PtrPack& P, int c, int o) { float s, t; bnst(P, 4, o, s, t); return s * P.p[2][o * 48 + c]; }
__device__ float w2r_v(const PtrPack& P, int o, int c) { float s, t; bnst(P, 10, o, s, t); return s * P.p[8][o * 24 + c]; }
__device__ float m_v(const PtrPack& P, int which, int c, int j) {
  float a = 0.f;
  if (which == 0)      for (int ok = 0; ok < 24; ok++) a += KFv(P, P.p[26], 28, ok, j) * WQf(P, ok, c);
  else if (which == 1) for (int ok = 0; ok < 24; ok++) a += KFv(P, P.p[26], 28, ok, j) * WQf(P, 24 + ok, c);
  else if (which == 2) for (int ok = 0; ok < 24; ok++) a += KFv(P, P.p[32], 34, ok, j) * WQf(P, ok, c);
  else                 for (int ok = 0; ok < 24; ok++) a += KFv(P, P.p[32], 34, ok, j) * WQf(P, 24 + ok, c);
  return a;
}
__device__ float p_v(const PtrPack& P, int which, int c, int o) {
  float a = 0.f;
  if (which == 0)      for (int jj = 0; jj < 24; jj++) a += P.p[44][o * 48 + jj] * WVf(P, jj, c);
  else if (which == 1) for (int jj = 0; jj < 24; jj++) a += P.p[44][o * 48 + jj] * WVf(P, 24 + jj, c);
  else if (which == 2) for (int jj = 0; jj < 24; jj++) a += P.p[44][o * 48 + 24 + jj] * WVf(P, jj, c);
  else                 for (int jj = 0; jj < 24; jj++) a += P.p[44][o * 48 + 24 + jj] * WVf(P, 24 + jj, c);
  return a;
}

__device__ __forceinline__ float packh2(float a, float b) {
  __half2 h = __floats2half2_rn(a, b);
  union { __half2 h; float f; } x; x.h = h;
  return x.f;
}

__global__ void fold_kernel(PtrPack P, float* __restrict__ W) {
  int i = blockIdx.x * blockDim.x + threadIdx.x;
  if (i >= WS_TOTAL) return;
  float s, t, a;
  if (i < OFF_B1)        { int j = i;           int c = j / 12, p = j % 12; W[i] = packh2(w1t_v(P, c, 2 * p), w1t_v(P, c, 2 * p + 1)); }
  else if (i < OFF_W2R)  { int o = i - OFF_B1;  bnst(P, 4, o, s, t); W[i] = s * P.p[3][o] + t; }
  else if (i < OFF_B2)   { int j = i - OFF_W2R; int o = j / 12, p = j % 12; W[i] = packh2(w2r_v(P, o, 2 * p), w2r_v(P, o, 2 * p + 1)); }
  else if (i < OFF_XS)   { int o = i - OFF_B2;  bnst(P, 10, o, s, t); W[i] = s * P.p[9][o] + t; }
  else if (i < OFF_M1A)  { int o = i - OFF_XS;  bnst(P, 10, o, s, t); W[i] = s; }
  else if (i < OFF_M1B)  { int j = i - OFF_M1A; int c = j / 12, p = j % 12; W[i] = packh2(m_v(P, 0, c, 2 * p), m_v(P, 0, c, 2 * p + 1)); }
  else if (i < OFF_M2A)  { int j = i - OFF_M1B; int c = j / 12, p = j % 12; W[i] = packh2(m_v(P, 1, c, 2 * p), m_v(P, 1, c, 2 * p + 1)); }
  else if (i < OFF_M2B)  { int j = i - OFF_M2A; int c = j / 12, p = j % 12; W[i] = packh2(m_v(P, 2, c, 2 * p), m_v(P, 2, c, 2 * p + 1)); }
  else if (i < OFF_C1A)  { int j = i - OFF_M2B; int c = j / 12, p = j % 12; W[i] = packh2(m_v(P, 3, c, 2 * p), m_v(P, 3, c, 2 * p + 1)); }
  else if (i < OFF_C1B)  { int c = i - OFF_C1A; a = 0.f; for (int ok = 0; ok < 24; ok++) a += BFv(P, P.p[26], P.p[27], 28, ok) * WQf(P, ok, c); W[i] = a; }
  else if (i < OFF_C2A)  { int c = i - OFF_C1B; a = 0.f; for (int ok = 0; ok < 24; ok++) a += BFv(P, P.p[26], P.p[27], 28, ok) * WQf(P, 24 + ok, c); W[i] = a; }
  else if (i < OFF_C2B)  { int c = i - OFF_C2A; a = 0.f; for (int ok = 0; ok < 24; ok++) a += BFv(P, P.p[32], P.p[33], 34, ok) * WQf(P, ok, c); W[i] = a; }
  else if (i < OFF_D1A)  { int c = i - OFF_C2B; a = 0.f; for (int ok = 0; ok < 24; ok++) a += BFv(P, P.p[32], P.p[33], 34, ok) * WQf(P, 24 + ok, c); W[i] = a; }
  else if (i < OFF_D1B)  { int j = i - OFF_D1A; a = 0.f; for (int ok = 0; ok < 24; ok++) a += KFv(P, P.p[26], 28, ok, j) * BQf(P, ok); W[i] = a; }
  else if (i < OFF_D2A)  { int j = i - OFF_D1B; a = 0.f; for (int ok = 0; ok < 24; ok++) a += KFv(P, P.p[26], 28, ok, j) * BQf(P, 24 + ok); W[i] = a; }
  else if (i < OFF_D2B)  { int j = i - OFF_D2A; a = 0.f; for (int ok = 0; ok < 24; ok++) a += KFv(P, P.p[32], 34, ok, j) * BQf(P, ok); W[i] = a; }
  else if (i < OFF_E4)   { int j = i - OFF_D2B; a = 0.f; for (int ok = 0; ok < 24; ok++) a += KFv(P, P.p[32], 34, ok, j) * BQf(P, 24 + ok); W[i] = a; }
  else if (i < OFF_P1L)  { int e = i - OFF_E4; a = 0.f;
    if (e == 0)      for (int ok = 0; ok < 24; ok++) a += BFv(P, P.p[26], P.p[27], 28, ok) * BQf(P, ok);
    else if (e == 1) for (int ok = 0; ok < 24; ok++) a += BFv(P, P.p[26], P.p[27], 28, ok) * BQf(P, 24 + ok);
    else if (e == 2) for (int ok = 0; ok < 24; ok++) a += BFv(P, P.p[32], P.p[33], 34, ok) * BQf(P, ok);
    else             for (int ok = 0; ok < 24; ok++) a += BFv(P, P.p[32], P.p[33], 34, ok) * BQf(P, 24 + ok);
    W[i] = a; }
  else if (i < OFF_P1H)  { int j = i - OFF_P1L; int c = j / 12, p = j % 12; W[i] = packh2(p_v(P, 0, c, 2 * p), p_v(P, 0, c, 2 * p + 1)); }
  else if (i < OFF_P2L)  { int j = i - OFF_P1H; int c = j / 12, p = j % 12; W[i] = packh2(p_v(P, 1, c, 2 * p), p_v(P, 1, c, 2 * p + 1)); }
  else if (i < OFF_P2H)  { int j = i - OFF_P2L; int c = j / 12, p = j % 12; W[i] = packh2(p_v(P, 2, c, 2 * p), p_v(P, 2, c, 2 * p + 1)); }
  else if (i < OFF_Q1L)  { int j = i - OFF_P2H; int c = j / 12, p = j % 12; W[i] = packh2(p_v(P, 3, c, 2 * p), p_v(P, 3, c, 2 * p + 1)); }
  else if (i < OFF_Q1H)  { int o = i - OFF_Q1L; a = 0.f; for (int jj = 0; jj < 24; jj++) a += P.p[44][o * 48 + jj] * BVf(P, jj); W[i] = a; }
  else if (i < OFF_Q2L)  { int o = i - OFF_Q1H; a = 0.f; for (int jj = 0; jj < 24; jj++) a += P.p[44][o * 48 + jj] * BVf(P, 24 + jj); W[i] = a; }
  else if (i < OFF_Q2H)  { int o = i - OFF_Q2L; a = 0.f; for (int jj = 0; jj < 24; jj++) a += P.p[44][o * 48 + 24 + jj] * BVf(P, jj); W[i] = a; }
  else if (i < OFF_BE1)  { int o = i - OFF_Q2H; a = 0.f; for (int jj = 0; jj < 24; jj++) a += P.p[44][o * 48 + 24 + jj] * BVf(P, 24 + jj); W[i] = a; }
  else if (i < OFF_CFT)  { int o = i - OFF_BE1; W[i] = P.p[45][o]; }
  else if (i < OFF_BCF)  { int j = i - OFF_CFT; int cin = j / 48, o = j % 48; bnst(P, 40, o, s, t); W[i] = s * P.p[38][o * 96 + cin]; }
  else if (i < OFF_WE1)  { int o = i - OFF_BCF; bnst(P, 40, o, s, t); W[i] = s * P.p[39][o] + t; }
  else if (i < OFF_BE2)  { int j = i - OFF_WE1; W[i] = P.p[44][j]; }
  else if (i < OFF_WE2R) { int o = i - OFF_BE2; W[i] = P.p[47][o]; }
  else                   { int j = i - OFF_WE2R; W[i] = P.p[46][j]; }
}

// ---------------- fused per-pixel forward ----------------

__device__ __forceinline__ float gelu_f(float x) {
  return 0.5f * x * (1.f + erff(x * 0.70710678118654752440f));
}
__device__ __forceinline__ __half2 ldh2(const float* __restrict__ W, int off) {
  union { float f; __half2 h; } x; x.f = W[off];
  return x.h;
}
__device__ __forceinline__ float flo(__half2 h) { return __half2float(__low2half(h)); }
__device__ __forceinline__ float fhi(__half2 h) { return __half2float(__high2half(h)); }

__global__ __launch_bounds__(T)
void fused_main(const float* __restrict__ x0g,
                const float* __restrict__ x1g,
                const float* __restrict__ W,
                float* __restrict__ out) {
  __shared__ __half2 Xh[2][24][T];
  const int tid = threadIdx.x;
  const int p = blockIdx.x * T + tid;
  const int b = p >> 14;
  const int n = p & (HWS - 1);

  {
    const float* px0 = x0g + (size_t)b * 48 * HWS + n;
    const float* px1 = x1g + (size_t)b * 48 * HWS + n;
#pragma unroll 1
    for (int cp = 0; cp < 24; cp++) {
      Xh[0][cp][tid] = __floats2half2_rn(px0[(size_t)(2 * cp) * HWS], px0[(size_t)(2 * cp + 1) * HWS]);
      Xh[1][cp][tid] = __floats2half2_rn(px1[(size_t)(2 * cp) * HWS], px1[(size_t)(2 * cp + 1) * HWS]);
    }
  }

  float h[24];

#pragma unroll 1
  for (int k = 0; k < 4; k++) {
    // ---- residual blocks ----
#pragma unroll 1
    for (int s = 0; s < 2; s++) {
      float r[24];
#pragma unroll
      for (int o = 0; o < 24; o++) r[o] = W[OFF_B1 + o];
#pragma unroll 2
      for (int cp = 0; cp < 24; cp++) {
        __half2 u = Xh[s][cp][tid];
        float xa = flo(u), xb = fhi(u);
#pragma unroll
        for (int op = 0; op < 12; op++) {
          __half2 w0 = ldh2(W, OFF_W1T + (2 * cp) * 12 + op);
          __half2 w1 = ldh2(W, OFF_W1T + (2 * cp + 1) * 12 + op);
          r[2 * op]     = fmaf(flo(w0), xa, r[2 * op]);
          r[2 * op + 1] = fmaf(fhi(w0), xa, r[2 * op + 1]);
          r[2 * op]     = fmaf(flo(w1), xb, r[2 * op]);
          r[2 * op + 1] = fmaf(fhi(w1), xb, r[2 * op + 1]);
        }
      }
#pragma unroll
      for (int o = 0; o < 24; o++) r[o] = fmaxf(r[o], 0.f);

#pragma unroll 2
      for (int op = 0; op < 24; op++) {
        float a0 = W[OFF_B2 + 2 * op], a1 = W[OFF_B2 + 2 * op + 1];
#pragma unroll
        for (int cj = 0; cj < 12; cj++) {
          __half2 wA = ldh2(W, OFF_W2R + (2 * op) * 12 + cj);
          __half2 wB = ldh2(W, OFF_W2R + (2 * op + 1) * 12 + cj);
          float rc0 = r[2 * cj], rc1 = r[2 * cj + 1];
          a0 = fmaf(flo(wA), rc0, a0); a0 = fmaf(fhi(wA), rc1, a0);
          a1 = fmaf(flo(wB), rc0, a1); a1 = fmaf(fhi(wB), rc1, a1);
        }
        __half2 u = Xh[s][op][tid];
        float n0 = fmaxf(fmaf(W[OFF_XS + 2 * op], flo(u), a0), 0.f);
        float n1 = fmaxf(fmaf(W[OFF_XS + 2 * op + 1], fhi(u), a1), 0.f);
        Xh[s][op][tid] = __floats2half2_rn(n0, n1);
      }
    }

    // ---- k==0: cf + emb1 -> h (fp32 tables) ----
    if (k == 0) {
      float tv[48];
#pragma unroll
      for (int o = 0; o < 48; o++) tv[o] = W[OFF_BCF + o];
#pragma unroll 1
      for (int s = 0; s < 2; s++) {
#pragma unroll 1
        for (int cp = 0; cp < 24; cp++) {
          __half2 u = Xh[s][cp][tid];
          float x0c = flo(u), x1c = fhi(u);
          const float* w0 = &W[OFF_CFT + (s * 48 + 2 * cp) * 48];
#pragma unroll
          for (int o = 0; o < 48; o++) tv[o] = fmaf(w0[o], x0c, tv[o]);
#pragma unroll
          for (int o = 0; o < 48; o++) tv[o] = fmaf(w0[48 + o], x1c, tv[o]);
        }
      }
#pragma unroll
      for (int o = 0; o < 48; o++) tv[o] = fmaxf(tv[o], 0.f);
#pragma unroll
      for (int o = 0; o < 24; o++) {
        float a = W[OFF_BE1 + o];
#pragma unroll
        for (int c = 0; c < 48; c++) a = fmaf(W[OFF_WE1 + o * 48 + c], tv[c], a);
        h[o] = gelu_f(a);
      }
    }

    // ---- scores ----
    float s1[4], s2[4];
    {
      float b1a = W[OFF_E4 + 0], b1b = W[OFF_E4 + 1], b2a = W[OFF_E4 + 2], b2b = W[OFF_E4 + 3];
#pragma unroll
      for (int j = 0; j < 24; j++) {
        b1a = fmaf(W[OFF_D1A + j], h[j], b1a);
        b1b = fmaf(W[OFF_D1B + j], h[j], b1b);
        b2a = fmaf(W[OFF_D2A + j], h[j], b2a);
        b2b = fmaf(W[OFF_D2B + j], h[j], b2b);
      }
      s1[0] = b1a; s1[2] = b1a; s1[1] = b1b; s1[3] = b1b;
      s2[0] = b2a; s2[2] = b2a; s2[1] = b2b; s2[3] = b2b;
    }
#pragma unroll 2
    for (int cp = 0; cp < 24; cp++) {
      __half2 u0 = Xh[0][cp][tid], u1 = Xh[1][cp][tid];
#pragma unroll
      for (int ch = 0; ch < 2; ch++) {
        const int c = 2 * cp + ch;
        float z1a = W[OFF_C1A + c], z1b = W[OFF_C1B + c];
        float z2a = W[OFF_C2A + c], z2b = W[OFF_C2B + c];
#pragma unroll
        for (int jp = 0; jp < 12; jp++) {
          __half2 wa = ldh2(W, OFF_M1A + c * 12 + jp);
          __half2 wb = ldh2(W, OFF_M1B + c * 12 + jp);
          __half2 wc = ldh2(W, OFF_M2A + c * 12 + jp);
          __half2 wd = ldh2(W, OFF_M2B + c * 12 + jp);
          float h0 = h[2 * jp], h1 = h[2 * jp + 1];
          z1a = fmaf(flo(wa), h0, z1a); z1a = fmaf(fhi(wa), h1, z1a);
          z1b = fmaf(flo(wb), h0, z1b); z1b = fmaf(fhi(wb), h1, z1b);
          z2a = fmaf(flo(wc), h0, z2a); z2a = fmaf(fhi(wc), h1, z2a);
          z2b = fmaf(flo(wd), h0, z2b); z2b = fmaf(fhi(wd), h1, z2b);
        }
        float x0 = ch ? fhi(u0) : flo(u0);
        float x1 = ch ? fhi(u1) : flo(u1);
        s1[0] = fmaf(x0, z1a, s1[0]); s1[1] = fmaf(x0, z1b, s1[1]);
        s1[2] = fmaf(x1, z1a, s1[2]); s1[3] = fmaf(x1, z1b, s1[3]);
        s2[0] = fmaf(x0, z2a, s2[0]); s2[1] = fmaf(x0, z2b, s2[1]);
        s2[2] = fmaf(x1, z2a, s2[2]); s2[3] = fmaf(x1, z2b, s2[3]);
      }
    }
    // softmax over 4
    {
      float m1 = fmaxf(fmaxf(s1[0], s1[1]), fmaxf(s1[2], s1[3]));
      float e0 = __expf(s1[0] - m1), e1 = __expf(s1[1] - m1), e2 = __expf(s1[2] - m1), e3 = __expf(s1[3] - m1);
      float inv = 1.f / (e0 + e1 + e2 + e3);
      s1[0] = e0 * inv; s1[1] = e1 * inv; s1[2] = e2 * inv; s1[3] = e3 * inv;
      float m2 = fmaxf(fmaxf(s2[0], s2[1]), fmaxf(s2[2], s2[3]));
      float f0 = __expf(s2[0] - m2), f1 = __expf(s2[1] - m2), f2 = __expf(s2[2] - m2), f3 = __expf(s2[3] - m2);
      float jnv = 1.f / (f0 + f1 + f2 + f3);
      s2[0] = f0 * jnv; s2[1] = f1 * jnv; s2[2] = f2 * jnv; s2[3] = f3 * jnv;
    }

    // ---- values fused with emb1 ----
    float hp[24];
    {
      float q1l = s1[0] + s1[2], q1h = s1[1] + s1[3];
      float q2l = s2[0] + s2[2], q2h = s2[1] + s2[3];
#pragma unroll
      for (int o = 0; o < 24; o++) {
        float a = W[OFF_BE1 + o];
        a = fmaf(q1l, W[OFF_Q1L + o], a);
        a = fmaf(q1h, W[OFF_Q1H + o], a);
        a = fmaf(q2l, W[OFF_Q2L + o], a);
        a = fmaf(q2h, W[OFF_Q2H + o], a);
        hp[o] = a;
      }
    }
#pragma unroll 2
    for (int cp = 0; cp < 24; cp++) {
      __half2 u0 = Xh[0][cp][tid], u1 = Xh[1][cp][tid];
#pragma unroll
      for (int ch = 0; ch < 2; ch++) {
        const int c = 2 * cp + ch;
        float x0 = ch ? fhi(u0) : flo(u0);
        float x1 = ch ? fhi(u1) : flo(u1);
        float cA = fmaf(s1[0], x0, s1[2] * x1);
        float cB = fmaf(s1[1], x0, s1[3] * x1);
        float cC = fmaf(s2[0], x0, s2[2] * x1);
        float cD = fmaf(s2[1], x0, s2[3] * x1);
#pragma unroll
        for (int opj = 0; opj < 12; opj++) {
          __half2 wa = ldh2(W, OFF_P1L + c * 12 + opj);
          __half2 wb = ldh2(W, OFF_P1H + c * 12 + opj);
          __half2 wc = ldh2(W, OFF_P2L + c * 12 + opj);
          __half2 wd = ldh2(W, OFF_P2H + c * 12 + opj);
          float t0 = hp[2 * opj], t1 = hp[2 * opj + 1];
          t0 = fmaf(flo(wa), cA, t0); t1 = fmaf(fhi(wa), cA, t1);
          t0 = fmaf(flo(wb), cB, t0); t1 = fmaf(fhi(wb), cB, t1);
          t0 = fmaf(flo(wc), cC, t0); t1 = fmaf(fhi(wc), cC, t1);
          t0 = fmaf(flo(wd), cD, t0); t1 = fmaf(fhi(wd), cD, t1);
          hp[2 * opj] = t0; hp[2 * opj + 1] = t1;
        }
      }
    }
#pragma unroll
    for (int o = 0; o < 24; o++) h[o] = gelu_f(hp[o]);
  }

  // ---- final: out = WE2 h + BE2 (fp32) ----
  float* po = out + (size_t)b * 48 * HWS + n;
#pragma unroll 1
  for (int op = 0; op < 24; op++) {
    const float* w0 = &W[OFF_WE2R + (2 * op) * 24];
    float a0 = W[OFF_BE2 + 2 * op], a1 = W[OFF_BE2 + 2 * op + 1];
#pragma unroll
    for (int j = 0; j < 24; j++) a0 = fmaf(w0[j], h[j], a0);
#pragma unroll
    for (int j = 0; j < 24; j++) a1 = fmaf(w0[24 + j], h[j], a1);
    po[(size_t)(2 * op) * HWS] = a0;
    po[(size_t)(2 * op + 1) * HWS] = a1;
  }
}

extern "C" void kernel_launch(void* const* d_in, const int* in_sizes, int n_in,
                              void* d_out, int out_size, void* d_ws, size_t ws_size,
                              hipStream_t stream) {
  PtrPack P;
  for (int i = 0; i < 48; i++) P.p[i] = (const float*)d_in[i];
  float* W = (float*)d_ws;

  fold_kernel<<<(WS_TOTAL + 255) / 256, 256, 0, stream>>>(P, W);
  fused_main<<<NPIX / T, T, 0, stream>>>(P.p[0], P.p[1], W, (float*)d_out);
}

// Round 11
// 779.962 us; speedup vs baseline: 1.2969x; 1.2969x over previous
//
#include <hip/hip_runtime.h>
#include <hip/hip_fp16.h>
#include <stdint.h>
#include <math.h>

#define HWS 16384
#define NPIX (16 * HWS)
#define T 256

// Folded fp32 table in d_ws (float offsets). Layouts chosen so every rolled
// loop reads contiguous rows.
enum {
  OFF_W1T  = 0,      // [48][24] c-major: rb conv1 (bn-folded)
  OFF_B1   = 1152,   // 24
  OFF_W2R  = 1176,   // [48][24] o-major rows: rb conv2
  OFF_B2   = 2328,   // 48
  OFF_XS   = 2376,   // 48
  OFF_M1A  = 2424,   // [48][24] c-major: score fold kk1/qh0
  OFF_M1B  = 3576,   // kk1/qh1
  OFF_M2A  = 4728,   // kk2/qh0
  OFF_M2B  = 5880,   // kk2/qh1
  OFF_C1A  = 7032,   // 48 each
  OFF_C1B  = 7080,
  OFF_C2A  = 7128,
  OFF_C2B  = 7176,
  OFF_D1A  = 7224,   // 24 each
  OFF_D1B  = 7248,
  OFF_D2A  = 7272,
  OFF_D2B  = 7296,
  OFF_E4   = 7320,   // 4 scalars e1a,e1b,e2a,e2b
  OFF_P1L  = 7324,   // [48][24] c-major: value->emb1 fold
  OFF_P1H  = 8476,
  OFF_P2L  = 9628,
  OFF_P2H  = 10780,
  OFF_Q1L  = 11932,  // 24 each (value-bias through WE1)
  OFF_Q1H  = 11956,
  OFF_Q2L  = 11980,
  OFF_Q2H  = 12004,
  OFF_BE1  = 12028,  // 24
  OFF_CFT  = 12052,  // [96][48] cin-major
  OFF_BCF  = 16660,  // 48
  OFF_WE1  = 16708,  // [24][48] o-major (k0 emb only)
  OFF_BE2  = 17860,  // 48
  OFF_WE2R = 17908,  // [48][24] o-major
  WS_TOTAL = 19060
};

struct PtrPack { const float* p[48]; };

__device__ __forceinline__ void bnst(const PtrPack& P, int bnb, int o, float& s, float& t) {
  float g = P.p[bnb][o], be = P.p[bnb + 1][o], m = P.p[bnb + 2][o], v = P.p[bnb + 3][o];
  s = g / sqrtf(v + 1e-5f);
  t = be - m * s;
}
// K-fold through WE2: K[ok][j] = s_k[ok] * sum_cc k_w[ok][cc] * we2[cc][j]
__device__ __forceinline__ float KFv(const PtrPack& P, const float* kw, int bnb, int ok, int j) {
  float s, t; bnst(P, bnb, ok, s, t);
  float a = 0.f;
  for (int cc = 0; cc < 48; cc++) a += kw[ok * 48 + cc] * P.p[46][cc * 24 + j];
  return s * a;
}
// K bias: s_k*(k_w . be2 + k_b) + t_k
__device__ __forceinline__ float BFv(const PtrPack& P, const float* kw, const float* kb, int bnb, int ok) {
  float s, t; bnst(P, bnb, ok, s, t);
  float a = kb[ok];
  for (int cc = 0; cc < 48; cc++) a += kw[ok * 48 + cc] * P.p[47][cc];
  return s * a + t;
}
__device__ __forceinline__ float WQf(const PtrPack& P, int o, int c) { float s, t; bnst(P, 16, o, s, t); return s * P.p[14][o * 48 + c]; }
__device__ __forceinline__ float BQf(const PtrPack& P, int o) { float s, t; bnst(P, 16, o, s, t); return s * P.p[15][o] + t; }
__device__ __forceinline__ float WVf(const PtrPack& P, int o, int c) { float s, t; bnst(P, 22, o, s, t); return s * P.p[20][o * 48 + c]; }
__device__ __forceinline__ float BVf(const PtrPack& P, int o) { float s, t; bnst(P, 22, o, s, t); return s * P.p[21][o] + t; }

__global__ void fold_kernel(PtrPack P, float* __restrict__ W) {
  int i = blockIdx.x * blockDim.x + threadIdx.x;
  if (i >= WS_TOTAL) return;
  float s, t, a;
  if (i < OFF_B1) { int c = i / 24, o = i % 24; bnst(P, 4, o, s, t); W[i] = s * P.p[2][o * 48 + c]; }
  else if (i < OFF_W2R) { int o = i - OFF_B1; bnst(P, 4, o, s, t); W[i] = s * P.p[3][o] + t; }
  else if (i < OFF_B2)  { int j = i - OFF_W2R; int o = j / 24, c = j % 24; bnst(P, 10, o, s, t); W[i] = s * P.p[8][o * 24 + c]; }
  else if (i < OFF_XS)  { int o = i - OFF_B2; bnst(P, 10, o, s, t); W[i] = s * P.p[9][o] + t; }
  else if (i < OFF_M1A) { int o = i - OFF_XS; bnst(P, 10, o, s, t); W[i] = s; }
  else if (i < OFF_M1B) { int j = i - OFF_M1A; int c = j / 24, jj = j % 24; a = 0.f;
    for (int ok = 0; ok < 24; ok++) a += KFv(P, P.p[26], 28, ok, jj) * WQf(P, ok, c); W[i] = a; }
  else if (i < OFF_M2A) { int j = i - OFF_M1B; int c = j / 24, jj = j % 24; a = 0.f;
    for (int ok = 0; ok < 24; ok++) a += KFv(P, P.p[26], 28, ok, jj) * WQf(P, 24 + ok, c); W[i] = a; }
  else if (i < OFF_M2B) { int j = i - OFF_M2A; int c = j / 24, jj = j % 24; a = 0.f;
    for (int ok = 0; ok < 24; ok++) a += KFv(P, P.p[32], 34, ok, jj) * WQf(P, ok, c); W[i] = a; }
  else if (i < OFF_C1A) { int j = i - OFF_M2B; int c = j / 24, jj = j % 24; a = 0.f;
    for (int ok = 0; ok < 24; ok++) a += KFv(P, P.p[32], 34, ok, jj) * WQf(P, 24 + ok, c); W[i] = a; }
  else if (i < OFF_C1B) { int c = i - OFF_C1A; a = 0.f;
    for (int ok = 0; ok < 24; ok++) a += BFv(P, P.p[26], P.p[27], 28, ok) * WQf(P, ok, c); W[i] = a; }
  else if (i < OFF_C2A) { int c = i - OFF_C1B; a = 0.f;
    for (int ok = 0; ok < 24; ok++) a += BFv(P, P.p[26], P.p[27], 28, ok) * WQf(P, 24 + ok, c); W[i] = a; }
  else if (i < OFF_C2B) { int c = i - OFF_C2A; a = 0.f;
    for (int ok = 0; ok < 24; ok++) a += BFv(P, P.p[32], P.p[33], 34, ok) * WQf(P, ok, c); W[i] = a; }
  else if (i < OFF_D1A) { int c = i - OFF_C2B; a = 0.f;
    for (int ok = 0; ok < 24; ok++) a += BFv(P, P.p[32], P.p[33], 34, ok) * WQf(P, 24 + ok, c); W[i] = a; }
  else if (i < OFF_D1B) { int jj = i - OFF_D1A; a = 0.f;
    for (int ok = 0; ok < 24; ok++) a += KFv(P, P.p[26], 28, ok, jj) * BQf(P, ok); W[i] = a; }
  else if (i < OFF_D2A) { int jj = i - OFF_D1B; a = 0.f;
    for (int ok = 0; ok < 24; ok++) a += KFv(P, P.p[26], 28, ok, jj) * BQf(P, 24 + ok); W[i] = a; }
  else if (i < OFF_D2B) { int jj = i - OFF_D2A; a = 0.f;
    for (int ok = 0; ok < 24; ok++) a += KFv(P, P.p[32], 34, ok, jj) * BQf(P, ok); W[i] = a; }
  else if (i < OFF_E4)  { int jj = i - OFF_D2B; a = 0.f;
    for (int ok = 0; ok < 24; ok++) a += KFv(P, P.p[32], 34, ok, jj) * BQf(P, 24 + ok); W[i] = a; }
  else if (i < OFF_P1L) { int e = i - OFF_E4; a = 0.f;
    if (e == 0)      for (int ok = 0; ok < 24; ok++) a += BFv(P, P.p[26], P.p[27], 28, ok) * BQf(P, ok);
    else if (e == 1) for (int ok = 0; ok < 24; ok++) a += BFv(P, P.p[26], P.p[27], 28, ok) * BQf(P, 24 + ok);
    else if (e == 2) for (int ok = 0; ok < 24; ok++) a += BFv(P, P.p[32], P.p[33], 34, ok) * BQf(P, ok);
    else             for (int ok = 0; ok < 24; ok++) a += BFv(P, P.p[32], P.p[33], 34, ok) * BQf(P, 24 + ok);
    W[i] = a; }
  else if (i < OFF_P1H) { int j = i - OFF_P1L; int c = j / 24, o = j % 24; a = 0.f;
    for (int jj = 0; jj < 24; jj++) a += P.p[44][o * 48 + jj] * WVf(P, jj, c); W[i] = a; }
  else if (i < OFF_P2L) { int j = i - OFF_P1H; int c = j / 24, o = j % 24; a = 0.f;
    for (int jj = 0; jj < 24; jj++) a += P.p[44][o * 48 + jj] * WVf(P, 24 + jj, c); W[i] = a; }
  else if (i < OFF_P2H) { int j = i - OFF_P2L; int c = j / 24, o = j % 24; a = 0.f;
    for (int jj = 0; jj < 24; jj++) a += P.p[44][o * 48 + 24 + jj] * WVf(P, jj, c); W[i] = a; }
  else if (i < OFF_Q1L) { int j = i - OFF_P2H; int c = j / 24, o = j % 24; a = 0.f;
    for (int jj = 0; jj < 24; jj++) a += P.p[44][o * 48 + 24 + jj] * WVf(P, 24 + jj, c); W[i] = a; }
  else if (i < OFF_Q1H) { int o = i - OFF_Q1L; a = 0.f;
    for (int jj = 0; jj < 24; jj++) a += P.p[44][o * 48 + jj] * BVf(P, jj); W[i] = a; }
  else if (i < OFF_Q2L) { int o = i - OFF_Q1H; a = 0.f;
    for (int jj = 0; jj < 24; jj++) a += P.p[44][o * 48 + jj] * BVf(P, 24 + jj); W[i] = a; }
  else if (i < OFF_Q2H) { int o = i - OFF_Q2L; a = 0.f;
    for (int jj = 0; jj < 24; jj++) a += P.p[44][o * 48 + 24 + jj] * BVf(P, jj); W[i] = a; }
  else if (i < OFF_BE1) { int o = i - OFF_Q2H; a = 0.f;
    for (int jj = 0; jj < 24; jj++) a += P.p[44][o * 48 + 24 + jj] * BVf(P, 24 + jj); W[i] = a; }
  else if (i < OFF_CFT) { int o = i - OFF_BE1; W[i] = P.p[45][o]; }
  else if (i < OFF_BCF) { int j = i - OFF_CFT; int cin = j / 48, o = j % 48; bnst(P, 40, o, s, t); W[i] = s * P.p[38][o * 96 + cin]; }
  else if (i < OFF_WE1) { int o = i - OFF_BCF; bnst(P, 40, o, s, t); W[i] = s * P.p[39][o] + t; }
  else if (i < OFF_BE2) { int j = i - OFF_WE1; W[i] = P.p[44][j]; }
  else if (i < OFF_WE2R){ int o = i - OFF_BE2; W[i] = P.p[47][o]; }
  else                  { int j = i - OFF_WE2R; W[i] = P.p[46][j]; }
}

// ---------------- fused per-pixel forward ----------------

__device__ __forceinline__ float gelu_f(float x) {
  return 0.5f * x * (1.f + erff(x * 0.70710678118654752440f));
}

__global__ __launch_bounds__(T)
void fused_main(const float* __restrict__ x0g,
                const float* __restrict__ x1g,
                const float* __restrict__ W,
                float* __restrict__ out) {
  __shared__ __half2 Xh[2][24][T];
  const int tid = threadIdx.x;
  const int p = blockIdx.x * T + tid;
  const int b = p >> 14;
  const int n = p & (HWS - 1);

  {
    const float* px0 = x0g + (size_t)b * 48 * HWS + n;
    const float* px1 = x1g + (size_t)b * 48 * HWS + n;
#pragma unroll 1
    for (int cp = 0; cp < 24; cp++) {
      Xh[0][cp][tid] = __floats2half2_rn(px0[(size_t)(2 * cp) * HWS], px0[(size_t)(2 * cp + 1) * HWS]);
      Xh[1][cp][tid] = __floats2half2_rn(px1[(size_t)(2 * cp) * HWS], px1[(size_t)(2 * cp + 1) * HWS]);
    }
  }

  float h[24];

#pragma unroll 1
  for (int k = 0; k < 4; k++) {
    // ---- residual blocks ----
#pragma unroll 1
    for (int s = 0; s < 2; s++) {
      float r[24];
#pragma unroll
      for (int o = 0; o < 24; o++) r[o] = W[OFF_B1 + o];
#pragma unroll 2
      for (int cp = 0; cp < 24; cp++) {
        __half2 u = Xh[s][cp][tid];
        float x0c = __low2float(u), x1c = __high2float(u);
        const float* w0 = &W[OFF_W1T + (2 * cp) * 24];
#pragma unroll
        for (int o = 0; o < 24; o++) r[o] = fmaf(w0[o], x0c, r[o]);
#pragma unroll
        for (int o = 0; o < 24; o++) r[o] = fmaf(w0[24 + o], x1c, r[o]);
      }
#pragma unroll
      for (int o = 0; o < 24; o++) r[o] = fmaxf(r[o], 0.f);

#pragma unroll 2
      for (int op = 0; op < 24; op++) {
        const float* w0 = &W[OFF_W2R + (2 * op) * 24];
        float a0 = W[OFF_B2 + 2 * op], a1 = W[OFF_B2 + 2 * op + 1];
#pragma unroll
        for (int c = 0; c < 24; c++) a0 = fmaf(w0[c], r[c], a0);
#pragma unroll
        for (int c = 0; c < 24; c++) a1 = fmaf(w0[24 + c], r[c], a1);
        __half2 u = Xh[s][op][tid];
        float n0 = fmaxf(fmaf(W[OFF_XS + 2 * op], __low2float(u), a0), 0.f);
        float n1 = fmaxf(fmaf(W[OFF_XS + 2 * op + 1], __high2float(u), a1), 0.f);
        Xh[s][op][tid] = __floats2half2_rn(n0, n1);
      }
    }

    // ---- k==0: cf + emb1 -> h ----
    if (k == 0) {
      float tv[48];
#pragma unroll
      for (int o = 0; o < 48; o++) tv[o] = W[OFF_BCF + o];
#pragma unroll 1
      for (int s = 0; s < 2; s++) {
#pragma unroll 1
        for (int cp = 0; cp < 24; cp++) {
          __half2 u = Xh[s][cp][tid];
          float x0c = __low2float(u), x1c = __high2float(u);
          const float* w0 = &W[OFF_CFT + (s * 48 + 2 * cp) * 48];
#pragma unroll
          for (int o = 0; o < 48; o++) tv[o] = fmaf(w0[o], x0c, tv[o]);
#pragma unroll
          for (int o = 0; o < 48; o++) tv[o] = fmaf(w0[48 + o], x1c, tv[o]);
        }
      }
#pragma unroll
      for (int o = 0; o < 48; o++) tv[o] = fmaxf(tv[o], 0.f);
      // h = gelu(WE1 tv + BE1)  (k0 only; fully unrolled, tv/h static)
#pragma unroll
      for (int o = 0; o < 24; o++) {
        float a = W[OFF_BE1 + o];
#pragma unroll
        for (int c = 0; c < 48; c++) a = fmaf(W[OFF_WE1 + o * 48 + c], tv[c], a);
        h[o] = gelu_f(a);
      }
    }

    // ---- scores: s(s,qh) = sum_c X_s[c]*(M[c].h + C[c]) + d.h + e ----
    float s1[4], s2[4];
    {
      float b1a = W[OFF_E4 + 0], b1b = W[OFF_E4 + 1], b2a = W[OFF_E4 + 2], b2b = W[OFF_E4 + 3];
#pragma unroll
      for (int j = 0; j < 24; j++) {
        b1a = fmaf(W[OFF_D1A + j], h[j], b1a);
        b1b = fmaf(W[OFF_D1B + j], h[j], b1b);
        b2a = fmaf(W[OFF_D2A + j], h[j], b2a);
        b2b = fmaf(W[OFF_D2B + j], h[j], b2b);
      }
      s1[0] = b1a; s1[2] = b1a; s1[1] = b1b; s1[3] = b1b;
      s2[0] = b2a; s2[2] = b2a; s2[1] = b2b; s2[3] = b2b;
    }
#pragma unroll 2
    for (int cp = 0; cp < 24; cp++) {
      __half2 u0 = Xh[0][cp][tid], u1 = Xh[1][cp][tid];
#pragma unroll
      for (int ch = 0; ch < 2; ch++) {
        int c = 2 * cp + ch;
        const float* m1a = &W[OFF_M1A + c * 24];
        const float* m1b = &W[OFF_M1B + c * 24];
        const float* m2a = &W[OFF_M2A + c * 24];
        const float* m2b = &W[OFF_M2B + c * 24];
        float z1a = W[OFF_C1A + c], z1b = W[OFF_C1B + c];
        float z2a = W[OFF_C2A + c], z2b = W[OFF_C2B + c];
#pragma unroll
        for (int j = 0; j < 24; j++) {
          z1a = fmaf(m1a[j], h[j], z1a);
          z1b = fmaf(m1b[j], h[j], z1b);
          z2a = fmaf(m2a[j], h[j], z2a);
          z2b = fmaf(m2b[j], h[j], z2b);
        }
        float x0 = ch ? __high2float(u0) : __low2float(u0);
        float x1 = ch ? __high2float(u1) : __low2float(u1);
        s1[0] = fmaf(x0, z1a, s1[0]); s1[1] = fmaf(x0, z1b, s1[1]);
        s1[2] = fmaf(x1, z1a, s1[2]); s1[3] = fmaf(x1, z1b, s1[3]);
        s2[0] = fmaf(x0, z2a, s2[0]); s2[1] = fmaf(x0, z2b, s2[1]);
        s2[2] = fmaf(x1, z2a, s2[2]); s2[3] = fmaf(x1, z2b, s2[3]);
      }
    }
    // softmax over 4
    {
      float m1 = fmaxf(fmaxf(s1[0], s1[1]), fmaxf(s1[2], s1[3]));
      float e0 = __expf(s1[0] - m1), e1 = __expf(s1[1] - m1), e2 = __expf(s1[2] - m1), e3 = __expf(s1[3] - m1);
      float inv = 1.f / (e0 + e1 + e2 + e3);
      s1[0] = e0 * inv; s1[1] = e1 * inv; s1[2] = e2 * inv; s1[3] = e3 * inv;
      float m2 = fmaxf(fmaxf(s2[0], s2[1]), fmaxf(s2[2], s2[3]));
      float f0 = __expf(s2[0] - m2), f1 = __expf(s2[1] - m2), f2 = __expf(s2[2] - m2), f3 = __expf(s2[3] - m2);
      float jnv = 1.f / (f0 + f1 + f2 + f3);
      s2[0] = f0 * jnv; s2[1] = f1 * jnv; s2[2] = f2 * jnv; s2[3] = f3 * jnv;
    }

    // ---- values fused with emb1: hp[o] = BE1 + bias-part + sum_c coef*P[c][o] ----
    float hp[24];
    {
      float q1l = s1[0] + s1[2], q1h = s1[1] + s1[3];
      float q2l = s2[0] + s2[2], q2h = s2[1] + s2[3];
#pragma unroll
      for (int o = 0; o < 24; o++) {
        float a = W[OFF_BE1 + o];
        a = fmaf(q1l, W[OFF_Q1L + o], a);
        a = fmaf(q1h, W[OFF_Q1H + o], a);
        a = fmaf(q2l, W[OFF_Q2L + o], a);
        a = fmaf(q2h, W[OFF_Q2H + o], a);
        hp[o] = a;
      }
    }
#pragma unroll 2
    for (int cp = 0; cp < 24; cp++) {
      __half2 u0 = Xh[0][cp][tid], u1 = Xh[1][cp][tid];
#pragma unroll
      for (int ch = 0; ch < 2; ch++) {
        int c = 2 * cp + ch;
        float x0 = ch ? __high2float(u0) : __low2float(u0);
        float x1 = ch ? __high2float(u1) : __low2float(u1);
        float cA = fmaf(s1[0], x0, s1[2] * x1);
        float cB = fmaf(s1[1], x0, s1[3] * x1);
        float cC = fmaf(s2[0], x0, s2[2] * x1);
        float cD = fmaf(s2[1], x0, s2[3] * x1);
        const float* p1l = &W[OFF_P1L + c * 24];
        const float* p1h = &W[OFF_P1H + c * 24];
        const float* p2l = &W[OFF_P2L + c * 24];
        const float* p2h = &W[OFF_P2H + c * 24];
#pragma unroll
        for (int o = 0; o < 24; o++) {
          float a = hp[o];
          a = fmaf(cA, p1l[o], a);
          a = fmaf(cB, p1h[o], a);
          a = fmaf(cC, p2l[o], a);
          a = fmaf(cD, p2h[o], a);
          hp[o] = a;
        }
      }
    }
#pragma unroll
    for (int o = 0; o < 24; o++) h[o] = gelu_f(hp[o]);
  }

  // ---- final: out = WE2 h + BE2 ----
  float* po = out + (size_t)b * 48 * HWS + n;
#pragma unroll 1
  for (int op = 0; op < 24; op++) {
    const float* w0 = &W[OFF_WE2R + (2 * op) * 24];
    float a0 = W[OFF_BE2 + 2 * op], a1 = W[OFF_BE2 + 2 * op + 1];
#pragma unroll
    for (int j = 0; j < 24; j++) a0 = fmaf(w0[j], h[j], a0);
#pragma unroll
    for (int j = 0; j < 24; j++) a1 = fmaf(w0[24 + j], h[j], a1);
    po[(size_t)(2 * op) * HWS] = a0;
    po[(size_t)(2 * op + 1) * HWS] = a1;
  }
}

extern "C" void kernel_launch(void* const* d_in, const int* in_sizes, int n_in,
                              void* d_out, int out_size, void* d_ws, size_t ws_size,
                              hipStream_t stream) {
  PtrPack P;
  for (int i = 0; i < 48; i++) P.p[i] = (const float*)d_in[i];
  float* W = (float*)d_ws;

  fold_kernel<<<(WS_TOTAL + 255) / 256, 256, 0, stream>>>(P, W);
  fused_main<<<NPIX / T, T, 0, stream>>>(P.p[0], P.p[1], W, (float*)d_out);
}

// Round 14
// 571.170 us; speedup vs baseline: 1.7710x; 1.3656x over previous
//
#include <hip/hip_runtime.h>
#include <hip/hip_fp16.h>
#include <stdint.h>
#include <math.h>

#define HWS 16384
#define NPIX (16 * HWS)
#define T 256

typedef _Float16 h2 __attribute__((ext_vector_type(2)));

// d_ws slot offsets (4B slots). H_* hold packed fp16 pairs; F_* are fp32.
enum {
  H_W1P = 0,     // [24cp][24o]  rb1, pair over input channels (matches X pairs)
  F_B1  = 576,   // 24
  H_W2P = 600,   // [48o][12cj]  rb2, pair over r channels
  F_B2  = 1176,  // 48
  F_XS  = 1224,  // 48
  H_M1A = 1272,  // [48c][12jp]  score folds, pair over h
  H_M1B = 1848,
  H_M2A = 2424,
  H_M2B = 3000,
  F_C1A = 3576, F_C1B = 3624, F_C2A = 3672, F_C2B = 3720,   // 48 each
  F_D1A = 3768, F_D1B = 3792, F_D2A = 3816, F_D2B = 3840,   // 24 each
  F_E4  = 3864,  // 4
  H_P1  = 3868,  // [48c][24o] = (p1l,p1h) pairs
  H_P2  = 5020,  // [48c][24o] = (p2l,p2h) pairs
  F_Q1L = 6172, F_Q1H = 6196, F_Q2L = 6220, F_Q2H = 6244,   // 24 each
  F_BE1 = 6268,  // 24
  F_CFT = 6292,  // f32 [96][48] (k0 only)
  F_BCF = 10900, // 48
  F_WE1 = 10948, // f32 [24][48] (k0 only)
  F_BE2 = 12100, // 48
  F_WE2R= 12148, // f32 [48][24] (final only)
  WS_TOTAL = 13300
};

struct PtrPack { const float* p[48]; };

__device__ __forceinline__ void bnst(const PtrPack& P, int bnb, int o, float& s, float& t) {
  float g = P.p[bnb][o], be = P.p[bnb + 1][o], m = P.p[bnb + 2][o], v = P.p[bnb + 3][o];
  s = g / sqrtf(v + 1e-5f);
  t = be - m * s;
}
__device__ __forceinline__ float KFv(const PtrPack& P, const float* kw, int bnb, int ok, int j) {
  float s, t; bnst(P, bnb, ok, s, t);
  float a = 0.f;
  for (int cc = 0; cc < 48; cc++) a += kw[ok * 48 + cc] * P.p[46][cc * 24 + j];
  return s * a;
}
__device__ __forceinline__ float BFv(const PtrPack& P, const float* kw, const float* kb, int bnb, int ok) {
  float s, t; bnst(P, bnb, ok, s, t);
  float a = kb[ok];
  for (int cc = 0; cc < 48; cc++) a += kw[ok * 48 + cc] * P.p[47][cc];
  return s * a + t;
}
__device__ __forceinline__ float WQf(const PtrPack& P, int o, int c) { float s, t; bnst(P, 16, o, s, t); return s * P.p[14][o * 48 + c]; }
__device__ __forceinline__ float BQf(const PtrPack& P, int o) { float s, t; bnst(P, 16, o, s, t); return s * P.p[15][o] + t; }
__device__ __forceinline__ float WVf(const PtrPack& P, int o, int c) { float s, t; bnst(P, 22, o, s, t); return s * P.p[20][o * 48 + c]; }
__device__ __forceinline__ float BVf(const PtrPack& P, int o) { float s, t; bnst(P, 22, o, s, t); return s * P.p[21][o] + t; }

__device__ float w1v(const PtrPack& P, int c, int o) { float s, t; bnst(P, 4, o, s, t); return s * P.p[2][o * 48 + c]; }
__device__ float w2v(const PtrPack& P, int o, int c) { float s, t; bnst(P, 10, o, s, t); return s * P.p[8][o * 24 + c]; }
__device__ float m_v(const PtrPack& P, int which, int c, int j) {
  float a = 0.f;
  if (which == 0)      for (int ok = 0; ok < 24; ok++) a += KFv(P, P.p[26], 28, ok, j) * WQf(P, ok, c);
  else if (which == 1) for (int ok = 0; ok < 24; ok++) a += KFv(P, P.p[26], 28, ok, j) * WQf(P, 24 + ok, c);
  else if (which == 2) for (int ok = 0; ok < 24; ok++) a += KFv(P, P.p[32], 34, ok, j) * WQf(P, ok, c);
  else                 for (int ok = 0; ok < 24; ok++) a += KFv(P, P.p[32], 34, ok, j) * WQf(P, 24 + ok, c);
  return a;
}
__device__ float p_v(const PtrPack& P, int which, int c, int o) {
  float a = 0.f;
  if (which == 0)      for (int jj = 0; jj < 24; jj++) a += P.p[44][o * 48 + jj] * WVf(P, jj, c);
  else if (which == 1) for (int jj = 0; jj < 24; jj++) a += P.p[44][o * 48 + jj] * WVf(P, 24 + jj, c);
  else if (which == 2) for (int jj = 0; jj < 24; jj++) a += P.p[44][o * 48 + 24 + jj] * WVf(P, jj, c);
  else                 for (int jj = 0; jj < 24; jj++) a += P.p[44][o * 48 + 24 + jj] * WVf(P, 24 + jj, c);
  return a;
}

__device__ __forceinline__ float packh2(float a, float b) {
  __half2 h = __floats2half2_rn(a, b);
  union { __half2 h; float f; } x; x.h = h; return x.f;
}

__global__ void fold_kernel(PtrPack P, float* __restrict__ W) {
  int i = blockIdx.x * blockDim.x + threadIdx.x;
  if (i >= WS_TOTAL) return;
  float s, t, a;
  if (i < F_B1)        { int cp = i / 24, o = i % 24; W[i] = packh2(w1v(P, 2 * cp, o), w1v(P, 2 * cp + 1, o)); }
  else if (i < H_W2P)  { int o = i - F_B1; bnst(P, 4, o, s, t); W[i] = s * P.p[3][o] + t; }
  else if (i < F_B2)   { int j = i - H_W2P; int o = j / 12, cj = j % 12; W[i] = packh2(w2v(P, o, 2 * cj), w2v(P, o, 2 * cj + 1)); }
  else if (i < F_XS)   { int o = i - F_B2; bnst(P, 10, o, s, t); W[i] = s * P.p[9][o] + t; }
  else if (i < H_M1A)  { int o = i - F_XS; bnst(P, 10, o, s, t); W[i] = s; }
  else if (i < H_M1B)  { int j = i - H_M1A; int c = j / 12, jp = j % 12; W[i] = packh2(m_v(P, 0, c, 2 * jp), m_v(P, 0, c, 2 * jp + 1)); }
  else if (i < H_M2A)  { int j = i - H_M1B; int c = j / 12, jp = j % 12; W[i] = packh2(m_v(P, 1, c, 2 * jp), m_v(P, 1, c, 2 * jp + 1)); }
  else if (i < H_M2B)  { int j = i - H_M2A; int c = j / 12, jp = j % 12; W[i] = packh2(m_v(P, 2, c, 2 * jp), m_v(P, 2, c, 2 * jp + 1)); }
  else if (i < F_C1A)  { int j = i - H_M2B; int c = j / 12, jp = j % 12; W[i] = packh2(m_v(P, 3, c, 2 * jp), m_v(P, 3, c, 2 * jp + 1)); }
  else if (i < F_C1B)  { int c = i - F_C1A; a = 0.f; for (int ok = 0; ok < 24; ok++) a += BFv(P, P.p[26], P.p[27], 28, ok) * WQf(P, ok, c); W[i] = a; }
  else if (i < F_C2A)  { int c = i - F_C1B; a = 0.f; for (int ok = 0; ok < 24; ok++) a += BFv(P, P.p[26], P.p[27], 28, ok) * WQf(P, 24 + ok, c); W[i] = a; }
  else if (i < F_C2B)  { int c = i - F_C2A; a = 0.f; for (int ok = 0; ok < 24; ok++) a += BFv(P, P.p[32], P.p[33], 34, ok) * WQf(P, ok, c); W[i] = a; }
  else if (i < F_D1A)  { int c = i - F_C2B; a = 0.f; for (int ok = 0; ok < 24; ok++) a += BFv(P, P.p[32], P.p[33], 34, ok) * WQf(P, 24 + ok, c); W[i] = a; }
  else if (i < F_D1B)  { int j = i - F_D1A; a = 0.f; for (int ok = 0; ok < 24; ok++) a += KFv(P, P.p[26], 28, ok, j) * BQf(P, ok); W[i] = a; }
  else if (i < F_D2A)  { int j = i - F_D1B; a = 0.f; for (int ok = 0; ok < 24; ok++) a += KFv(P, P.p[26], 28, ok, j) * BQf(P, 24 + ok); W[i] = a; }
  else if (i < F_D2B)  { int j = i - F_D2A; a = 0.f; for (int ok = 0; ok < 24; ok++) a += KFv(P, P.p[32], 34, ok, j) * BQf(P, ok); W[i] = a; }
  else if (i < F_E4)   { int j = i - F_D2B; a = 0.f; for (int ok = 0; ok < 24; ok++) a += KFv(P, P.p[32], 34, ok, j) * BQf(P, 24 + ok); W[i] = a; }
  else if (i < H_P1)   { int e = i - F_E4; a = 0.f;
    if (e == 0)      for (int ok = 0; ok < 24; ok++) a += BFv(P, P.p[26], P.p[27], 28, ok) * BQf(P, ok);
    else if (e == 1) for (int ok = 0; ok < 24; ok++) a += BFv(P, P.p[26], P.p[27], 28, ok) * BQf(P, 24 + ok);
    else if (e == 2) for (int ok = 0; ok < 24; ok++) a += BFv(P, P.p[32], P.p[33], 34, ok) * BQf(P, ok);
    else             for (int ok = 0; ok < 24; ok++) a += BFv(P, P.p[32], P.p[33], 34, ok) * BQf(P, 24 + ok);
    W[i] = a; }
  else if (i < H_P2)   { int j = i - H_P1; int c = j / 24, o = j % 24; W[i] = packh2(p_v(P, 0, c, o), p_v(P, 1, c, o)); }
  else if (i < F_Q1L)  { int j = i - H_P2; int c = j / 24, o = j % 24; W[i] = packh2(p_v(P, 2, c, o), p_v(P, 3, c, o)); }
  else if (i < F_Q1H)  { int o = i - F_Q1L; a = 0.f; for (int jj = 0; jj < 24; jj++) a += P.p[44][o * 48 + jj] * BVf(P, jj); W[i] = a; }
  else if (i < F_Q2L)  { int o = i - F_Q1H; a = 0.f; for (int jj = 0; jj < 24; jj++) a += P.p[44][o * 48 + jj] * BVf(P, 24 + jj); W[i] = a; }
  else if (i < F_Q2H)  { int o = i - F_Q2L; a = 0.f; for (int jj = 0; jj < 24; jj++) a += P.p[44][o * 48 + 24 + jj] * BVf(P, jj); W[i] = a; }
  else if (i < F_BE1)  { int o = i - F_Q2H; a = 0.f; for (int jj = 0; jj < 24; jj++) a += P.p[44][o * 48 + 24 + jj] * BVf(P, 24 + jj); W[i] = a; }
  else if (i < F_CFT)  { int o = i - F_BE1; W[i] = P.p[45][o]; }
  else if (i < F_BCF)  { int j = i - F_CFT; int cin = j / 48, o = j % 48; bnst(P, 40, o, s, t); W[i] = s * P.p[38][o * 96 + cin]; }
  else if (i < F_WE1)  { int o = i - F_BCF; bnst(P, 40, o, s, t); W[i] = s * P.p[39][o] + t; }
  else if (i < F_BE2)  { int j = i - F_WE1; W[i] = P.p[44][j]; }
  else if (i < F_WE2R) { int o = i - F_BE2; W[i] = P.p[47][o]; }
  else                 { int j = i - F_WE2R; W[i] = P.p[46][j]; }
}

// ---------------- fused per-pixel forward (dot2 hot loops) ----------------

__device__ __forceinline__ float gelu_f(float x) {
  return 0.5f * x * (1.f + erff(x * 0.70710678118654752440f));
}
__device__ __forceinline__ float fdot2f(h2 a, h2 b, float c) {
#if __has_builtin(__builtin_amdgcn_fdot2)
  return __builtin_amdgcn_fdot2(a, b, c, false);
#else
  return fmaf((float)a[0], (float)b[0], fmaf((float)a[1], (float)b[1], c));
#endif
}
__device__ __forceinline__ h2 ldh(const float* __restrict__ W, int off) {
  union { float f; h2 h; } u; u.f = W[off]; return u.h;
}
__device__ __forceinline__ h2 ash2(__half2 v) {
  union { __half2 a; h2 h; } u; u.a = v; return u.h;
}
// Round-to-nearest-even packing (NOT pkrtz — RTZ's biased truncation pushed
// absmax from 0.094 to 0.174 in round 13).
__device__ __forceinline__ h2 pk(float a, float b) {
  return ash2(__floats2half2_rn(a, b));
}

__global__ __launch_bounds__(T)
void fused_main(const float* __restrict__ x0g,
                const float* __restrict__ x1g,
                const float* __restrict__ W,
                float* __restrict__ out) {
  __shared__ __half2 Xh[2][24][T];
  const int tid = threadIdx.x;
  const int p = blockIdx.x * T + tid;
  const int b = p >> 14;
  const int n = p & (HWS - 1);

  {
    const float* px0 = x0g + (size_t)b * 48 * HWS + n;
    const float* px1 = x1g + (size_t)b * 48 * HWS + n;
#pragma unroll 1
    for (int cp = 0; cp < 24; cp++) {
      Xh[0][cp][tid] = __floats2half2_rn(px0[(size_t)(2 * cp) * HWS], px0[(size_t)(2 * cp + 1) * HWS]);
      Xh[1][cp][tid] = __floats2half2_rn(px1[(size_t)(2 * cp) * HWS], px1[(size_t)(2 * cp + 1) * HWS]);
    }
  }

  float h[24];

#pragma unroll 1
  for (int k = 0; k < 4; k++) {
    // ---- residual blocks ----
#pragma unroll 1
    for (int s = 0; s < 2; s++) {
      float r[24];
#pragma unroll
      for (int o = 0; o < 24; o++) r[o] = W[F_B1 + o];
#pragma unroll 2
      for (int cp = 0; cp < 24; cp++) {
        h2 xp = ash2(Xh[s][cp][tid]);
#pragma unroll
        for (int o = 0; o < 24; o++) r[o] = fdot2f(ldh(W, H_W1P + cp * 24 + o), xp, r[o]);
      }
#pragma unroll
      for (int o = 0; o < 24; o++) r[o] = fmaxf(r[o], 0.f);
      h2 rp[12];
#pragma unroll
      for (int j = 0; j < 12; j++) rp[j] = pk(r[2 * j], r[2 * j + 1]);

#pragma unroll 2
      for (int op = 0; op < 24; op++) {
        float a0 = W[F_B2 + 2 * op], a1 = W[F_B2 + 2 * op + 1];
#pragma unroll
        for (int cj = 0; cj < 12; cj++) a0 = fdot2f(ldh(W, H_W2P + (2 * op) * 12 + cj), rp[cj], a0);
#pragma unroll
        for (int cj = 0; cj < 12; cj++) a1 = fdot2f(ldh(W, H_W2P + (2 * op + 1) * 12 + cj), rp[cj], a1);
        __half2 u = Xh[s][op][tid];
        float n0 = fmaxf(fmaf(W[F_XS + 2 * op], __low2float(u), a0), 0.f);
        float n1 = fmaxf(fmaf(W[F_XS + 2 * op + 1], __high2float(u), a1), 0.f);
        Xh[s][op][tid] = __floats2half2_rn(n0, n1);
      }
    }

    // ---- k==0: cf + emb1 -> h (fp32 tables, runs once) ----
    if (k == 0) {
      float tv[48];
#pragma unroll
      for (int o = 0; o < 48; o++) tv[o] = W[F_BCF + o];
#pragma unroll 1
      for (int s = 0; s < 2; s++) {
#pragma unroll 1
        for (int cp = 0; cp < 24; cp++) {
          __half2 u = Xh[s][cp][tid];
          float x0c = __low2float(u), x1c = __high2float(u);
          const float* w0 = &W[F_CFT + (s * 48 + 2 * cp) * 48];
#pragma unroll
          for (int o = 0; o < 48; o++) tv[o] = fmaf(w0[o], x0c, tv[o]);
#pragma unroll
          for (int o = 0; o < 48; o++) tv[o] = fmaf(w0[48 + o], x1c, tv[o]);
        }
      }
#pragma unroll
      for (int o = 0; o < 48; o++) tv[o] = fmaxf(tv[o], 0.f);
#pragma unroll
      for (int o = 0; o < 24; o++) {
        float a = W[F_BE1 + o];
#pragma unroll
        for (int c = 0; c < 48; c++) a = fmaf(W[F_WE1 + o * 48 + c], tv[c], a);
        h[o] = gelu_f(a);
      }
    }

    // ---- scores ----
    float s1[4], s2[4];
    {
      float b1a = W[F_E4 + 0], b1b = W[F_E4 + 1], b2a = W[F_E4 + 2], b2b = W[F_E4 + 3];
#pragma unroll
      for (int j = 0; j < 24; j++) {
        b1a = fmaf(W[F_D1A + j], h[j], b1a);
        b1b = fmaf(W[F_D1B + j], h[j], b1b);
        b2a = fmaf(W[F_D2A + j], h[j], b2a);
        b2b = fmaf(W[F_D2B + j], h[j], b2b);
      }
      s1[0] = b1a; s1[2] = b1a; s1[1] = b1b; s1[3] = b1b;
      s2[0] = b2a; s2[2] = b2a; s2[1] = b2b; s2[3] = b2b;
    }
    h2 hp[12];
#pragma unroll
    for (int j = 0; j < 12; j++) hp[j] = pk(h[2 * j], h[2 * j + 1]);

#pragma unroll 2
    for (int cp = 0; cp < 24; cp++) {
      __half2 u0 = Xh[0][cp][tid], u1 = Xh[1][cp][tid];
#pragma unroll
      for (int ch = 0; ch < 2; ch++) {
        int c = 2 * cp + ch;
        float z1a = W[F_C1A + c], z1b = W[F_C1B + c];
        float z2a = W[F_C2A + c], z2b = W[F_C2B + c];
#pragma unroll
        for (int jp = 0; jp < 12; jp++) {
          z1a = fdot2f(ldh(W, H_M1A + c * 12 + jp), hp[jp], z1a);
          z1b = fdot2f(ldh(W, H_M1B + c * 12 + jp), hp[jp], z1b);
          z2a = fdot2f(ldh(W, H_M2A + c * 12 + jp), hp[jp], z2a);
          z2b = fdot2f(ldh(W, H_M2B + c * 12 + jp), hp[jp], z2b);
        }
        float x0 = ch ? __high2float(u0) : __low2float(u0);
        float x1 = ch ? __high2float(u1) : __low2float(u1);
        s1[0] = fmaf(x0, z1a, s1[0]); s1[1] = fmaf(x0, z1b, s1[1]);
        s1[2] = fmaf(x1, z1a, s1[2]); s1[3] = fmaf(x1, z1b, s1[3]);
        s2[0] = fmaf(x0, z2a, s2[0]); s2[1] = fmaf(x0, z2b, s2[1]);
        s2[2] = fmaf(x1, z2a, s2[2]); s2[3] = fmaf(x1, z2b, s2[3]);
      }
    }
    // softmax over 4
    {
      float m1 = fmaxf(fmaxf(s1[0], s1[1]), fmaxf(s1[2], s1[3]));
      float e0 = __expf(s1[0] - m1), e1 = __expf(s1[1] - m1), e2 = __expf(s1[2] - m1), e3 = __expf(s1[3] - m1);
      float inv = 1.f / (e0 + e1 + e2 + e3);
      s1[0] = e0 * inv; s1[1] = e1 * inv; s1[2] = e2 * inv; s1[3] = e3 * inv;
      float m2 = fmaxf(fmaxf(s2[0], s2[1]), fmaxf(s2[2], s2[3]));
      float f0 = __expf(s2[0] - m2), f1 = __expf(s2[1] - m2), f2 = __expf(s2[2] - m2), f3 = __expf(s2[3] - m2);
      float jnv = 1.f / (f0 + f1 + f2 + f3);
      s2[0] = f0 * jnv; s2[1] = f1 * jnv; s2[2] = f2 * jnv; s2[3] = f3 * jnv;
    }

    // ---- values fused with emb1 ----
    float hv[24];
    {
      float q1l = s1[0] + s1[2], q1h = s1[1] + s1[3];
      float q2l = s2[0] + s2[2], q2h = s2[1] + s2[3];
#pragma unroll
      for (int o = 0; o < 24; o++) {
        float a = W[F_BE1 + o];
        a = fmaf(q1l, W[F_Q1L + o], a);
        a = fmaf(q1h, W[F_Q1H + o], a);
        a = fmaf(q2l, W[F_Q2L + o], a);
        a = fmaf(q2h, W[F_Q2H + o], a);
        hv[o] = a;
      }
    }
#pragma unroll 2
    for (int cp = 0; cp < 24; cp++) {
      __half2 u0 = Xh[0][cp][tid], u1 = Xh[1][cp][tid];
#pragma unroll
      for (int ch = 0; ch < 2; ch++) {
        int c = 2 * cp + ch;
        float x0 = ch ? __high2float(u0) : __low2float(u0);
        float x1 = ch ? __high2float(u1) : __low2float(u1);
        float cA = fmaf(s1[0], x0, s1[2] * x1);
        float cB = fmaf(s1[1], x0, s1[3] * x1);
        float cC = fmaf(s2[0], x0, s2[2] * x1);
        float cD = fmaf(s2[1], x0, s2[3] * x1);
        h2 pAB = pk(cA, cB), pCD = pk(cC, cD);
#pragma unroll
        for (int o = 0; o < 24; o++) {
          float a = hv[o];
          a = fdot2f(ldh(W, H_P1 + c * 24 + o), pAB, a);
          a = fdot2f(ldh(W, H_P2 + c * 24 + o), pCD, a);
          hv[o] = a;
        }
      }
    }
#pragma unroll
    for (int o = 0; o < 24; o++) h[o] = gelu_f(hv[o]);
  }

  // ---- final: out = WE2 h + BE2 (fp32) ----
  float* po = out + (size_t)b * 48 * HWS + n;
#pragma unroll 1
  for (int op = 0; op < 24; op++) {
    const float* w0 = &W[F_WE2R + (2 * op) * 24];
    float a0 = W[F_BE2 + 2 * op], a1 = W[F_BE2 + 2 * op + 1];
#pragma unroll
    for (int j = 0; j < 24; j++) a0 = fmaf(w0[j], h[j], a0);
#pragma unroll
    for (int j = 0; j < 24; j++) a1 = fmaf(w0[24 + j], h[j], a1);
    po[(size_t)(2 * op) * HWS] = a0;
    po[(size_t)(2 * op + 1) * HWS] = a1;
  }
}

extern "C" void kernel_launch(void* const* d_in, const int* in_sizes, int n_in,
                              void* d_out, int out_size, void* d_ws, size_t ws_size,
                              hipStream_t stream) {
  PtrPack P;
  for (int i = 0; i < 48; i++) P.p[i] = (const float*)d_in[i];
  float* W = (float*)d_ws;

  fold_kernel<<<(WS_TOTAL + 255) / 256, 256, 0, stream>>>(P, W);
  fused_main<<<NPIX / T, T, 0, stream>>>(P.p[0], P.p[1], W, (float*)d_out);
}